// Round 5
// baseline (567.433 us; speedup 1.0000x reference)
//
#include <hip/hip_runtime.h>
#include <type_traits>

typedef __attribute__((ext_vector_type(8))) short short8;
typedef __attribute__((ext_vector_type(4))) float float4v;

__device__ inline float bf2f(short s) {
    unsigned u = ((unsigned)(unsigned short)s) << 16;
    float f; __builtin_memcpy(&f, &u, 4); return f;
}
__device__ inline short f2bf(float f) {
    unsigned u; __builtin_memcpy(&u, &f, 4);
    unsigned lsb = (u >> 16) & 1;
    u += 0x7fffu + lsb;
    return (short)(u >> 16);
}

// async global->LDS, 16B per lane; lds dest must be wave-uniform base (HW adds lane*16)
__device__ inline void glds16(const void* g, void* l) {
    __builtin_amdgcn_global_load_lds(
        (const __attribute__((address_space(1))) unsigned int*)g,
        (__attribute__((address_space(3))) unsigned int*)l, 16, 0, 0);
}

// ---------------------------------------------------------------------------
// f32 -> bf16 elementwise (x pre-conversion). 8 elems/thread.
// ---------------------------------------------------------------------------
__global__ __launch_bounds__(256) void conv_f32_bf16(const float* __restrict__ in,
                                                     short* __restrict__ out, int n8) {
    int idx = blockIdx.x * 256 + threadIdx.x;
    if (idx >= n8) return;
    const float* src = in + (size_t)idx * 8;
    float4v a = *(const float4v*)src;
    float4v b = *(const float4v*)(src + 4);
    short8 o;
#pragma unroll
    for (int j = 0; j < 4; j++) { o[j] = f2bf(a[j]); o[4 + j] = f2bf(b[j]); }
    *(short8*)(out + (size_t)idx * 8) = o;
}

// ---------------------------------------------------------------------------
// Transpose + convert: in f32 (K x ldn), column slice [noff, noff+Ntile) ->
// out bf16 (Ntile x K). 64x64 tiles.
// ---------------------------------------------------------------------------
__global__ __launch_bounds__(256) void transpose_conv(const float* __restrict__ in,
                                                      short* __restrict__ out,
                                                      int K, int ldn, int noff) {
    __shared__ float t[64 * 65];
    const int n0 = blockIdx.x * 64, k0 = blockIdx.y * 64;
    const int tid = threadIdx.x;
#pragma unroll
    for (int i = 0; i < 4; i++) {
        int slot = tid + 256 * i;
        int row = slot >> 4, c4 = slot & 15;
        float4v v = *(const float4v*)(in + (size_t)(k0 + row) * ldn + noff + n0 + c4 * 4);
#pragma unroll
        for (int j = 0; j < 4; j++) t[row * 65 + c4 * 4 + j] = v[j];
    }
    __syncthreads();
#pragma unroll
    for (int i = 0; i < 2; i++) {
        int slot = tid + 256 * i;
        int row = slot >> 3, c8 = slot & 7;
        short8 v;
#pragma unroll
        for (int j = 0; j < 8; j++) v[j] = f2bf(t[(c8 * 8 + j) * 65 + row]);
        *(short8*)(out + (size_t)(n0 + row) * K + k0 + c8 * 8) = v;
    }
}

// ---------------------------------------------------------------------------
// bf16 transpose: in (K x N, row stride ldin) -> out (N x K), 64x64 tiles
// ---------------------------------------------------------------------------
__global__ __launch_bounds__(256) void transpose_k(const short* __restrict__ in,
                                                   short* __restrict__ out,
                                                   int K, int N, int ldin) {
    __attribute__((aligned(16))) __shared__ short t[64 * 72];
    const int n0 = blockIdx.x * 64, k0 = blockIdx.y * 64;
    const int tid = threadIdx.x;
#pragma unroll
    for (int i = 0; i < 2; i++) {
        int slot = tid + 256 * i;
        int row = slot >> 3, c8 = slot & 7;
        *(short8*)&t[row * 72 + c8 * 8] =
            *(const short8*)(in + (size_t)(k0 + row) * ldin + n0 + c8 * 8);
    }
    __syncthreads();
#pragma unroll
    for (int i = 0; i < 2; i++) {
        int slot = tid + 256 * i;
        int row = slot >> 3, c8 = slot & 7;
        short8 v;
#pragma unroll
        for (int j = 0; j < 8; j++) v[j] = t[(c8 * 8 + j) * 72 + row];
        *(short8*)(out + (size_t)(n0 + row) * K + k0 + c8 * 8) = v;
    }
}

// ---------------------------------------------------------------------------
// Deep-pipelined GEMM, templated tile: C = A (2048 x 4096 bf16) * Bt^T.
// MF = m-frags/wave (4 -> BM=128, 2 -> BM=64); NB = N/256 n-blocks.
// 8 waves (2M x 4N); per-wave MF*16 x 64 output. Grid: 256 blocks (1/CU),
// XCD-bijective swizzle. LDS: 2 x (BM+256) x 64 bf16 double buffer.
// Staging via global_load_lds w16, 2-tile lookahead, counted vmcnt at loop
// top (never drains in steady state), raw s_barrier. T2 chunk-XOR swizzle
// via pre-swizzled global source + swizzled ds_read (same involution).
// Hang-safety: all staged addresses in-bounds for every t; uniform barriers.
// ---------------------------------------------------------------------------
template <int MF, int NB, typename CT>
__global__ __launch_bounds__(512) void gemm_bt_p(const short* __restrict__ A,
                                                 const short* __restrict__ Bt,
                                                 CT* __restrict__ C) {
    constexpr int BM = MF * 32;          // 128 or 64
    constexpr int LDC = NB * 256;        // 4096 or 2048
    constexpr int APASS = BM / 64;       // glds passes for A tile (2 or 1)
    __attribute__((aligned(16))) __shared__ short lds[2][(BM + 256) * 64];
    const int tid = threadIdx.x;
    const int lane = tid & 63, wave = tid >> 6;
    const int quad = lane >> 4, l16 = lane & 15;
    const int wm = wave >> 2, wn = wave & 3;
    const int b = blockIdx.x;
    const int sw = (b & 7) * 32 + (b >> 3);   // XCD-bijective (256 % 8 == 0)
    const int n0 = (sw % NB) * 256;
    const int m0 = (sw / NB) * BM;
    const int lr = lane >> 3, lc = lane & 7;
    const int swc = lc ^ lr;             // pre-swizzled source chunk (involution)
    const int K = 4096;

    float4v acc[MF][4];
#pragma unroll
    for (int i = 0; i < MF; i++)
#pragma unroll
        for (int j = 0; j < 4; j++) acc[i][j] = (float4v){0.f, 0.f, 0.f, 0.f};

    auto stage = [&](int t, int buf) {
        const int k0 = t * 64;
        short* Ab = &lds[buf][0];
        short* Bb = &lds[buf][BM * 64];
#pragma unroll
        for (int p = 0; p < APASS; p++) {
            int row = p * 64 + wave * 8;  // wave-uniform LDS base row
            glds16(A + (size_t)(m0 + row + lr) * K + k0 + swc * 8, Ab + row * 64);
        }
#pragma unroll
        for (int p = 0; p < 4; p++) {
            int row = p * 64 + wave * 8;
            glds16(Bt + (size_t)(n0 + row + lr) * K + k0 + swc * 8, Bb + row * 64);
        }
    };

    stage(0, 0);
    stage(1, 1);

    for (int t = 0; t < 64; t++) {
        // tile t resident after waiting out all but next tile's loads
        if (t + 1 < 64) {
            if constexpr (APASS == 2) asm volatile("s_waitcnt vmcnt(6)" ::: "memory");
            else                      asm volatile("s_waitcnt vmcnt(5)" ::: "memory");
        } else {
            asm volatile("s_waitcnt vmcnt(0)" ::: "memory");
        }
        __builtin_amdgcn_sched_barrier(0);
        __builtin_amdgcn_s_barrier();
        asm volatile("" ::: "memory");
        const short* As = &lds[t & 1][0];
        const short* Bs = &lds[t & 1][BM * 64];
        short8 af[MF][2], bf[4][2];
#pragma unroll
        for (int mf = 0; mf < MF; mf++)
#pragma unroll
            for (int kc = 0; kc < 2; kc++)
                af[mf][kc] = *(const short8*)&As[(wm * MF * 16 + mf * 16 + l16) * 64 +
                                                 (((kc * 4 + quad) ^ (l16 & 7)) * 8)];
#pragma unroll
        for (int nf = 0; nf < 4; nf++)
#pragma unroll
            for (int kc = 0; kc < 2; kc++)
                bf[nf][kc] = *(const short8*)&Bs[(wn * 64 + nf * 16 + l16) * 64 +
                                                 (((kc * 4 + quad) ^ (l16 & 7)) * 8)];
        __builtin_amdgcn_s_setprio(1);
#pragma unroll
        for (int mf = 0; mf < MF; mf++)
#pragma unroll
            for (int nf = 0; nf < 4; nf++)
#pragma unroll
                for (int kc = 0; kc < 2; kc++)
                    acc[mf][nf] = __builtin_amdgcn_mfma_f32_16x16x32_bf16(
                        af[mf][kc], bf[nf][kc], acc[mf][nf], 0, 0, 0);
        __builtin_amdgcn_s_setprio(0);
        asm volatile("" ::: "memory");
        __builtin_amdgcn_s_barrier();   // all waves done reading buf[t&1]
        asm volatile("" ::: "memory");
        if (t + 2 < 64) stage(t + 2, t & 1);
    }

    // C layout: col = lane&15, row = quad*4 + reg
#pragma unroll
    for (int mf = 0; mf < MF; mf++)
#pragma unroll
        for (int nf = 0; nf < 4; nf++) {
            int col = n0 + wn * 64 + nf * 16 + l16;
#pragma unroll
            for (int r = 0; r < 4; r++) {
                int row = m0 + wm * MF * 16 + mf * 16 + quad * 4 + r;
                if constexpr (std::is_same<CT, float>::value)
                    C[(size_t)row * LDC + col] = acc[mf][nf][r];
                else
                    C[(size_t)row * LDC + col] = f2bf(acc[mf][nf][r]);
            }
        }
}

// ---------------------------------------------------------------------------
// GEMM (m97 structure): C(:, coff + [0,Nt)) = A (MxK) * Bt^T, Bt (Nt x K) bf16.
// 128x128 tile, BK=64, 4 waves 2x2. Used by fallback plans only.
// ---------------------------------------------------------------------------
template <typename AT, typename CT>
__global__ __launch_bounds__(256) void gemm_bt_g(const AT* __restrict__ A,
                                                 const short* __restrict__ Bt,
                                                 CT* __restrict__ C,
                                                 int K, int ldc, int coff) {
    __attribute__((aligned(16))) __shared__ short As[128 * 64];
    __attribute__((aligned(16))) __shared__ short Bs[128 * 64];
    const int tid = threadIdx.x;
    const int lane = tid & 63, wave = tid >> 6;
    const int quad = lane >> 4, l16 = lane & 15;
    const int wr = wave >> 1, wc = wave & 1;
    const int m0 = blockIdx.y * 128, n0 = blockIdx.x * 128;
    const int lrow = lane >> 3, lc8 = lane & 7;

    float4v acc[4][4];
#pragma unroll
    for (int i = 0; i < 4; i++)
#pragma unroll
        for (int j = 0; j < 4; j++) acc[i][j] = (float4v){0.f, 0.f, 0.f, 0.f};

    for (int k0 = 0; k0 < K; k0 += 64) {
#pragma unroll
        for (int r = 0; r < 4; r++) {
            int slab = r * 4 + wave;
            glds16(Bt + (size_t)(n0 + slab * 8 + lrow) * K + k0 + lc8 * 8, &Bs[slab * 512]);
        }
        if constexpr (std::is_same<AT, short>::value) {
#pragma unroll
            for (int r = 0; r < 4; r++) {
                int slab = r * 4 + wave;
                glds16(A + (size_t)(m0 + slab * 8 + lrow) * K + k0 + lc8 * 8, &As[slab * 512]);
            }
        } else {
#pragma unroll
            for (int i = 0; i < 4; i++) {
                int slot = tid + 256 * i;
                int row = slot >> 3, c8 = slot & 7;
                const float* src = A + (size_t)(m0 + row) * K + k0 + c8 * 8;
                float4v a = *(const float4v*)src;
                float4v b = *(const float4v*)(src + 4);
                short8 o;
#pragma unroll
                for (int j = 0; j < 4; j++) { o[j] = f2bf(a[j]); o[4 + j] = f2bf(b[j]); }
                *(short8*)&As[row * 64 + c8 * 8] = o;
            }
        }
        __syncthreads();
#pragma unroll
        for (int kc = 0; kc < 2; kc++) {
            short8 afr[4], bfr[4];
#pragma unroll
            for (int rt = 0; rt < 4; rt++)
                afr[rt] = *(const short8*)&As[(wr * 64 + rt * 16 + l16) * 64 + kc * 32 + quad * 8];
#pragma unroll
            for (int ct = 0; ct < 4; ct++)
                bfr[ct] = *(const short8*)&Bs[(wc * 64 + ct * 16 + l16) * 64 + kc * 32 + quad * 8];
#pragma unroll
            for (int rt = 0; rt < 4; rt++)
#pragma unroll
                for (int ct = 0; ct < 4; ct++)
                    acc[rt][ct] = __builtin_amdgcn_mfma_f32_16x16x32_bf16(
                        afr[rt], bfr[ct], acc[rt][ct], 0, 0, 0);
        }
        __syncthreads();
    }
#pragma unroll
    for (int rt = 0; rt < 4; rt++)
#pragma unroll
        for (int ct = 0; ct < 4; ct++) {
            int col = coff + n0 + wc * 64 + ct * 16 + l16;
#pragma unroll
            for (int r = 0; r < 4; r++) {
                int row = m0 + wr * 64 + rt * 16 + quad * 4 + r;
                if constexpr (std::is_same<CT, float>::value)
                    C[(size_t)row * ldc + col] = acc[rt][ct][r];
                else
                    C[(size_t)row * ldc + col] = f2bf(acc[rt][ct][r]);
            }
        }
}

// ---------------------------------------------------------------------------
// RoPE (interleaved pairs), in-place on (S, rows of ld) bf16; freqs f32.
// ---------------------------------------------------------------------------
__global__ void rope_kernel(short* __restrict__ T, const float* __restrict__ cosb,
                            const float* __restrict__ sinb, int nheads, int ld) {
    int idx = blockIdx.x * 256 + threadIdx.x;
    int total = 2048 * nheads * 16;
    if (idx >= total) return;
    int chunk = idx & 15;
    int t2 = idx >> 4;
    int hh = t2 % nheads;
    int s = t2 / nheads;
    short* p = T + (size_t)s * ld + hh * 128 + chunk * 8;
    short8 v = *(short8*)p;
    short8 o;
#pragma unroll
    for (int t = 0; t < 4; t++) {
        int i = chunk * 4 + t;
        float c = cosb[s * 64 + i];
        float sn = sinb[s * 64 + i];
        float a = bf2f(v[2 * t]), b = bf2f(v[2 * t + 1]);
        o[2 * t] = f2bf(a * c - b * sn);
        o[2 * t + 1] = f2bf(a * sn + b * c);
    }
    *(short8*)p = o;
}

// ---------------------------------------------------------------------------
// Flash attention v3: grid (16, 32). Block processes q-tiles {i, 31-i}
// sequentially -> exactly 33 KV iterations at KVBLK=64 (balanced).
// 4 waves x 16 q-rows. K/V LDS double-buffered -> ONE __syncthreads per
// iteration (full rendezvous separates prev reads from next writes).
// XOR slot swizzle both sides. Reg prefetch of tile t+1 issued before
// compute, written to LDS after compute. exp2-domain softmax + T13
// defer-rescale (skip o_acc rescale when max doesn't grow).
// O may alias Q (block writes exactly the q rows it read).
// ---------------------------------------------------------------------------
__global__ __launch_bounds__(256) void attn_kernel(const short* __restrict__ Q,
                                                   const short* __restrict__ K,
                                                   const short* __restrict__ Vt,
                                                   short* __restrict__ O, int ldk) {
    __attribute__((aligned(16))) __shared__ short Ks[2][64 * 128];   // [kv][d] swizzled
    __attribute__((aligned(16))) __shared__ short Vs[2][128 * 64];   // [d][kv] swizzled
    __attribute__((aligned(16))) __shared__ short Ps[4][16 * 72];
    const int tid = threadIdx.x;
    const int lane = tid & 63, wave = tid >> 6;
    const int quad = lane >> 4, l16 = lane & 15;
    const int h = blockIdx.y, kvh = h >> 2;
    // scale * log2(e): softmax in exp2 domain
    const float scale2 = 0.08838834764831845f * 1.4426950408889634f;

    for (int pass = 0; pass < 2; pass++) {
        const int qtile = pass ? (31 - (int)blockIdx.x) : (int)blockIdx.x;
        const int qbase = qtile * 64;
        const int q0 = qbase + wave * 16;
        const int nt = qtile + 1;

        short8 qf[4];
        const short* qrow = Q + (size_t)(q0 + l16) * 4096 + h * 128;
#pragma unroll
        for (int ks = 0; ks < 4; ks++) qf[ks] = *(const short8*)(qrow + ks * 32 + quad * 8);

        float4v o_acc[8];
#pragma unroll
        for (int i = 0; i < 8; i++) o_acc[i] = (float4v){0.f, 0.f, 0.f, 0.f};
        float m_i[4], l_i[4];
#pragma unroll
        for (int r = 0; r < 4; r++) { m_i[r] = -1e9f; l_i[r] = 0.f; }

        // prologue: tile 0 -> regs; sync (prev pass readers done); -> buf0
        short8 kreg[4], vreg[4];
#pragma unroll
        for (int i = 0; i < 4; i++) {
            int slot = tid + 256 * i;
            int row = slot >> 4, c8 = slot & 15;
            kreg[i] = *(const short8*)(K + (size_t)row * ldk + kvh * 128 + c8 * 8);
        }
#pragma unroll
        for (int i = 0; i < 4; i++) {
            int slot = tid + 256 * i;
            int row = slot >> 3, c8 = slot & 7;
            vreg[i] = *(const short8*)(Vt + (size_t)(kvh * 128 + row) * 2048 + c8 * 8);
        }
        __syncthreads();
#pragma unroll
        for (int i = 0; i < 4; i++) {
            int slot = tid + 256 * i;
            int row = slot >> 4, c8 = slot & 15;
            *(short8*)&Ks[0][row * 128 + ((c8 ^ (row & 15)) * 8)] = kreg[i];
        }
#pragma unroll
        for (int i = 0; i < 4; i++) {
            int slot = tid + 256 * i;
            int row = slot >> 3, c8 = slot & 7;
            *(short8*)&Vs[0][row * 64 + ((c8 ^ (row & 7)) * 8)] = vreg[i];
        }

        for (int t = 0; t < nt; t++) {
            const int kv0 = t * 64;
            const int cur = t & 1;
            __syncthreads();  // buf[cur] writes visible; all prev reads done
            const bool pf = (t + 1 < nt);
            if (pf) {
                const int kv1 = kv0 + 64;
#pragma unroll
                for (int i = 0; i < 4; i++) {
                    int slot = tid + 256 * i;
                    int row = slot >> 4, c8 = slot & 15;
                    kreg[i] = *(const short8*)(K + (size_t)(kv1 + row) * ldk + kvh * 128 + c8 * 8);
                }
#pragma unroll
                for (int i = 0; i < 4; i++) {
                    int slot = tid + 256 * i;
                    int row = slot >> 3, c8 = slot & 7;
                    vreg[i] = *(const short8*)(Vt + (size_t)(kvh * 128 + row) * 2048 + kv1 + c8 * 8);
                }
            }

            // ---- QK^T: 16 MFMA ----
            float4v s_acc[4];
#pragma unroll
            for (int i = 0; i < 4; i++) s_acc[i] = (float4v){0.f, 0.f, 0.f, 0.f};
            __builtin_amdgcn_s_setprio(1);
#pragma unroll
            for (int nsub = 0; nsub < 4; nsub++) {
                const int row = nsub * 16 + l16;  // row & 15 == l16
#pragma unroll
                for (int ks = 0; ks < 4; ks++) {
                    short8 kf = *(const short8*)&Ks[cur][row * 128 + (((ks * 4 + quad) ^ l16) * 8)];
                    s_acc[nsub] = __builtin_amdgcn_mfma_f32_16x16x32_bf16(
                        qf[ks], kf, s_acc[nsub], 0, 0, 0);
                }
            }
            __builtin_amdgcn_s_setprio(0);

            // ---- online softmax (exp2 domain) ----
            const bool diag = (t == nt - 1);
            float p[4][4];
#pragma unroll
            for (int nsub = 0; nsub < 4; nsub++)
#pragma unroll
                for (int r = 0; r < 4; r++) {
                    float v = s_acc[nsub][r] * scale2;
                    if (diag) {
                        int rowq = q0 + quad * 4 + r;
                        int col = kv0 + nsub * 16 + l16;
                        v = (col <= rowq) ? v : -1e9f;
                    }
                    p[nsub][r] = v;
                }
            float tm[4];
#pragma unroll
            for (int r = 0; r < 4; r++)
                tm[r] = fmaxf(fmaxf(p[0][r], p[1][r]), fmaxf(p[2][r], p[3][r]));
#pragma unroll
            for (int off = 1; off < 16; off <<= 1)
#pragma unroll
                for (int r = 0; r < 4; r++)
                    tm[r] = fmaxf(tm[r], __shfl_xor(tm[r], off, 64));
            int ok = 1;
#pragma unroll
            for (int r = 0; r < 4; r++) ok &= (tm[r] <= m_i[r]);
            const bool need = !__all(ok);   // T13: rescale only if max grew
            float alpha[4];
            if (need) {
#pragma unroll
                for (int r = 0; r < 4; r++) {
                    float mn = fmaxf(m_i[r], tm[r]);
                    alpha[r] = __builtin_amdgcn_exp2f(m_i[r] - mn);
                    m_i[r] = mn;
                }
            }
            float rs[4];
#pragma unroll
            for (int r = 0; r < 4; r++) rs[r] = 0.f;
#pragma unroll
            for (int nsub = 0; nsub < 4; nsub++)
#pragma unroll
                for (int r = 0; r < 4; r++) {
                    float e = __builtin_amdgcn_exp2f(p[nsub][r] - m_i[r]);
                    rs[r] += e;
                    Ps[wave][(quad * 4 + r) * 72 + nsub * 16 + l16] = f2bf(e);
                }
#pragma unroll
            for (int off = 1; off < 16; off <<= 1)
#pragma unroll
                for (int r = 0; r < 4; r++) rs[r] += __shfl_xor(rs[r], off, 64);
            if (need) {
#pragma unroll
                for (int r = 0; r < 4; r++) l_i[r] = l_i[r] * alpha[r] + rs[r];
#pragma unroll
                for (int dt = 0; dt < 8; dt++)
#pragma unroll
                    for (int r = 0; r < 4; r++) o_acc[dt][r] *= alpha[r];
            } else {
#pragma unroll
                for (int r = 0; r < 4; r++) l_i[r] += rs[r];
            }

            // ---- PV: 16 MFMA ----
            short8 pf0 = *(const short8*)&Ps[wave][l16 * 72 + quad * 8];
            short8 pf1 = *(const short8*)&Ps[wave][l16 * 72 + 32 + quad * 8];
            __builtin_amdgcn_s_setprio(1);
#pragma unroll
            for (int dt = 0; dt < 8; dt++) {
                const int row = dt * 16 + l16;
                short8 vf0 = *(const short8*)&Vs[cur][row * 64 + ((quad ^ (l16 & 7)) * 8)];
                short8 vf1 = *(const short8*)&Vs[cur][row * 64 + (((4 + quad) ^ (l16 & 7)) * 8)];
                o_acc[dt] = __builtin_amdgcn_mfma_f32_16x16x32_bf16(pf0, vf0, o_acc[dt], 0, 0, 0);
                o_acc[dt] = __builtin_amdgcn_mfma_f32_16x16x32_bf16(pf1, vf1, o_acc[dt], 0, 0, 0);
            }
            __builtin_amdgcn_s_setprio(0);

            // ---- write tile t+1 into the other buffer (reads of it were
            //      separated by this iteration's top sync) ----
            if (pf) {
#pragma unroll
                for (int i = 0; i < 4; i++) {
                    int slot = tid + 256 * i;
                    int row = slot >> 4, c8 = slot & 15;
                    *(short8*)&Ks[cur ^ 1][row * 128 + ((c8 ^ (row & 15)) * 8)] = kreg[i];
                }
#pragma unroll
                for (int i = 0; i < 4; i++) {
                    int slot = tid + 256 * i;
                    int row = slot >> 3, c8 = slot & 7;
                    *(short8*)&Vs[cur ^ 1][row * 64 + ((c8 ^ (row & 7)) * 8)] = vreg[i];
                }
            }
        }

#pragma unroll
        for (int dt = 0; dt < 8; dt++)
#pragma unroll
            for (int r = 0; r < 4; r++) {
                int rowq = q0 + quad * 4 + r;
                O[(size_t)rowq * 4096 + h * 128 + dt * 16 + l16] = f2bf(o_acc[dt][r] / l_i[r]);
            }
    }
}

// ---------------------------------------------------------------------------
// Host. Workspace plans (adaptive on ws_size):
//  A (>=76MB): xb[0,16) Qb[16,32) KVb[32,40) Vt[40,44) WT[44,76)
//     Q/O proj: gemm_bt_p<4,16>; KV: gemm_bt_p<2,8> (all 256 blocks, 1/CU)
//  B (>=60MB): WT 16MB, Q/O proj in two N=2048 slices (old gemm)
//  C (else, 36MB): f32-A reg-staged gemms, 1024-col slices
// d_out is FLOAT32 (2048x4096 f32).
// ---------------------------------------------------------------------------
extern "C" void kernel_launch(void* const* d_in, const int* in_sizes, int n_in,
                              void* d_out, int out_size, void* d_ws, size_t ws_size,
                              hipStream_t stream) {
    (void)in_sizes; (void)n_in; (void)out_size;
    const float* x  = (const float*)d_in[0];
    const float* wq = (const float*)d_in[1];
    const float* wk = (const float*)d_in[2];
    const float* wv = (const float*)d_in[3];
    const float* wo = (const float*)d_in[4];
    const float* fc = (const float*)d_in[5];
    const float* fs = (const float*)d_in[6];
    float* out = (float*)d_out;
    char* ws = (char*)d_ws;
    const size_t MB = 1ull << 20;

    if (ws_size >= 76 * MB) {
        short* xb  = (short*)(ws);
        short* Qb  = (short*)(ws + 16 * MB);
        short* KVb = (short*)(ws + 32 * MB);
        short* Vt  = (short*)(ws + 40 * MB);
        short* WT  = (short*)(ws + 44 * MB);
        conv_f32_bf16<<<4096, 256, 0, stream>>>(x, xb, 2048 * 4096 / 8);
        transpose_conv<<<dim3(64, 64), 256, 0, stream>>>(wq, WT, 4096, 4096, 0);
        gemm_bt_p<4, 16, short><<<256, 512, 0, stream>>>(xb, WT, Qb);
        transpose_conv<<<dim3(16, 64), 256, 0, stream>>>(wk, WT, 4096, 1024, 0);
        transpose_conv<<<dim3(16, 64), 256, 0, stream>>>(wv, WT + (size_t)1024 * 4096, 4096, 1024, 0);
        gemm_bt_p<2, 8, short><<<256, 512, 0, stream>>>(xb, WT, KVb);
        rope_kernel<<<4096, 256, 0, stream>>>(Qb, fc, fs, 32, 4096);
        rope_kernel<<<1024, 256, 0, stream>>>(KVb, fc, fs, 8, 2048);
        transpose_k<<<dim3(16, 32), 256, 0, stream>>>(KVb + 1024, Vt, 2048, 1024, 2048);
        attn_kernel<<<dim3(16, 32), 256, 0, stream>>>(Qb, KVb, Vt, Qb, 2048);
        transpose_conv<<<dim3(64, 64), 256, 0, stream>>>(wo, WT, 4096, 4096, 0);
        gemm_bt_p<4, 16, float><<<256, 512, 0, stream>>>(Qb, WT, out);
    } else if (ws_size >= 60 * MB) {
        short* xb  = (short*)(ws);
        short* Qb  = (short*)(ws + 16 * MB);
        short* KVb = (short*)(ws + 32 * MB);
        short* Vt  = (short*)(ws + 40 * MB);
        short* WT  = (short*)(ws + 44 * MB);
        conv_f32_bf16<<<4096, 256, 0, stream>>>(x, xb, 2048 * 4096 / 8);
        for (int s = 0; s < 2; s++) {
            transpose_conv<<<dim3(32, 64), 256, 0, stream>>>(wq, WT, 4096, 4096, s * 2048);
            gemm_bt_g<short, short><<<dim3(16, 16), 256, 0, stream>>>(xb, WT, Qb, 4096, 4096, s * 2048);
        }
        transpose_conv<<<dim3(16, 64), 256, 0, stream>>>(wk, WT, 4096, 1024, 0);
        transpose_conv<<<dim3(16, 64), 256, 0, stream>>>(wv, WT + (size_t)1024 * 4096, 4096, 1024, 0);
        gemm_bt_g<short, short><<<dim3(16, 16), 256, 0, stream>>>(xb, WT, KVb, 4096, 2048, 0);
        rope_kernel<<<4096, 256, 0, stream>>>(Qb, fc, fs, 32, 4096);
        rope_kernel<<<1024, 256, 0, stream>>>(KVb, fc, fs, 8, 2048);
        transpose_k<<<dim3(16, 32), 256, 0, stream>>>(KVb + 1024, Vt, 2048, 1024, 2048);
        attn_kernel<<<dim3(16, 32), 256, 0, stream>>>(Qb, KVb, Vt, Qb, 2048);
        for (int s = 0; s < 2; s++) {
            transpose_conv<<<dim3(32, 64), 256, 0, stream>>>(wo, WT, 4096, 4096, s * 2048);
            gemm_bt_g<short, float><<<dim3(16, 16), 256, 0, stream>>>(Qb, WT, out, 4096, 4096, s * 2048);
        }
    } else {
        short* WT = (short*)(ws);
        short* Qb = (short*)(ws + 8 * MB);
        short* Kb = (short*)(ws + 24 * MB);
        short* Vb = (short*)(ws + 28 * MB);
        short* Vt = (short*)(ws + 32 * MB);
        for (int s = 0; s < 4; s++) {
            transpose_conv<<<dim3(16, 64), 256, 0, stream>>>(wq, WT, 4096, 4096, s * 1024);
            gemm_bt_g<float, short><<<dim3(8, 16), 256, 0, stream>>>(x, WT, Qb, 4096, 4096, s * 1024);
        }
        transpose_conv<<<dim3(16, 64), 256, 0, stream>>>(wk, WT, 4096, 1024, 0);
        gemm_bt_g<float, short><<<dim3(8, 16), 256, 0, stream>>>(x, WT, Kb, 4096, 1024, 0);
        transpose_conv<<<dim3(16, 64), 256, 0, stream>>>(wv, WT, 4096, 1024, 0);
        gemm_bt_g<float, short><<<dim3(8, 16), 256, 0, stream>>>(x, WT, Vb, 4096, 1024, 0);
        rope_kernel<<<4096, 256, 0, stream>>>(Qb, fc, fs, 32, 4096);
        rope_kernel<<<1024, 256, 0, stream>>>(Kb, fc, fs, 8, 1024);
        transpose_k<<<dim3(16, 32), 256, 0, stream>>>(Vb, Vt, 2048, 1024, 1024);
        attn_kernel<<<dim3(16, 32), 256, 0, stream>>>(Qb, Kb, Vt, Qb, 1024);
        for (int s = 0; s < 4; s++) {
            transpose_conv<<<dim3(16, 64), 256, 0, stream>>>(wo, WT, 4096, 4096, s * 1024);
            gemm_bt_g<short, float><<<dim3(8, 16), 256, 0, stream>>>(Qb, WT, out, 4096, 4096, s * 1024);
        }
    }
}

// Round 6
// 563.702 us; speedup vs baseline: 1.0066x; 1.0066x over previous
//
#include <hip/hip_runtime.h>
#include <type_traits>

typedef __attribute__((ext_vector_type(8))) short short8;
typedef __attribute__((ext_vector_type(4))) float float4v;

__device__ inline float bf2f(short s) {
    unsigned u = ((unsigned)(unsigned short)s) << 16;
    float f; __builtin_memcpy(&f, &u, 4); return f;
}
__device__ inline short f2bf(float f) {
    unsigned u; __builtin_memcpy(&u, &f, 4);
    unsigned lsb = (u >> 16) & 1;
    u += 0x7fffu + lsb;
    return (short)(u >> 16);
}

// async global->LDS, 16B per lane; lds dest must be wave-uniform base (HW adds lane*16)
__device__ inline void glds16(const void* g, void* l) {
    __builtin_amdgcn_global_load_lds(
        (const __attribute__((address_space(1))) unsigned int*)g,
        (__attribute__((address_space(3))) unsigned int*)l, 16, 0, 0);
}

// ---------------------------------------------------------------------------
// f32 -> bf16 elementwise (x pre-conversion). 8 elems/thread.
// ---------------------------------------------------------------------------
__global__ __launch_bounds__(256) void conv_f32_bf16(const float* __restrict__ in,
                                                     short* __restrict__ out, int n8) {
    int idx = blockIdx.x * 256 + threadIdx.x;
    if (idx >= n8) return;
    const float* src = in + (size_t)idx * 8;
    float4v a = *(const float4v*)src;
    float4v b = *(const float4v*)(src + 4);
    short8 o;
#pragma unroll
    for (int j = 0; j < 4; j++) { o[j] = f2bf(a[j]); o[4 + j] = f2bf(b[j]); }
    *(short8*)(out + (size_t)idx * 8) = o;
}

// ---------------------------------------------------------------------------
// Transpose + convert: in f32 (K x ldn), column slice [noff, noff+Ntile) ->
// out bf16 (Ntile x K). 64x64 tiles.
// ---------------------------------------------------------------------------
__global__ __launch_bounds__(256) void transpose_conv(const float* __restrict__ in,
                                                      short* __restrict__ out,
                                                      int K, int ldn, int noff) {
    __shared__ float t[64 * 65];
    const int n0 = blockIdx.x * 64, k0 = blockIdx.y * 64;
    const int tid = threadIdx.x;
#pragma unroll
    for (int i = 0; i < 4; i++) {
        int slot = tid + 256 * i;
        int row = slot >> 4, c4 = slot & 15;
        float4v v = *(const float4v*)(in + (size_t)(k0 + row) * ldn + noff + n0 + c4 * 4);
#pragma unroll
        for (int j = 0; j < 4; j++) t[row * 65 + c4 * 4 + j] = v[j];
    }
    __syncthreads();
#pragma unroll
    for (int i = 0; i < 2; i++) {
        int slot = tid + 256 * i;
        int row = slot >> 3, c8 = slot & 7;
        short8 v;
#pragma unroll
        for (int j = 0; j < 8; j++) v[j] = f2bf(t[(c8 * 8 + j) * 65 + row]);
        *(short8*)(out + (size_t)(n0 + row) * K + k0 + c8 * 8) = v;
    }
}

// ---------------------------------------------------------------------------
// bf16 transpose: in (K x N, row stride ldin) -> out (N x K), 64x64 tiles
// ---------------------------------------------------------------------------
__global__ __launch_bounds__(256) void transpose_k(const short* __restrict__ in,
                                                   short* __restrict__ out,
                                                   int K, int N, int ldin) {
    __attribute__((aligned(16))) __shared__ short t[64 * 72];
    const int n0 = blockIdx.x * 64, k0 = blockIdx.y * 64;
    const int tid = threadIdx.x;
#pragma unroll
    for (int i = 0; i < 2; i++) {
        int slot = tid + 256 * i;
        int row = slot >> 3, c8 = slot & 7;
        *(short8*)&t[row * 72 + c8 * 8] =
            *(const short8*)(in + (size_t)(k0 + row) * ldin + n0 + c8 * 8);
    }
    __syncthreads();
#pragma unroll
    for (int i = 0; i < 2; i++) {
        int slot = tid + 256 * i;
        int row = slot >> 3, c8 = slot & 7;
        short8 v;
#pragma unroll
        for (int j = 0; j < 8; j++) v[j] = t[(c8 * 8 + j) * 72 + row];
        *(short8*)(out + (size_t)(n0 + row) * K + k0 + c8 * 8) = v;
    }
}

// ---------------------------------------------------------------------------
// Deep-pipelined GEMM, templated tile: C = A (2048 x 4096 bf16) * Bt^T.
// MF = m-frags/wave (4 -> BM=128, 2 -> BM=64); NB = N/256 n-blocks.
// 8 waves (2M x 4N); per-wave MF*16 x 64 output. Grid: 256 blocks (1/CU),
// XCD-bijective swizzle. LDS: 2 x (BM+256) x 64 bf16 double buffer.
// Staging via global_load_lds w16, 2-tile lookahead, counted vmcnt at loop
// top (never drains in steady state), raw s_barrier. T2 chunk-XOR swizzle
// via pre-swizzled global source + swizzled ds_read (same involution).
// Hang-safety: all staged addresses in-bounds for every t; uniform barriers.
// ---------------------------------------------------------------------------
template <int MF, int NB, typename CT>
__global__ __launch_bounds__(512) void gemm_bt_p(const short* __restrict__ A,
                                                 const short* __restrict__ Bt,
                                                 CT* __restrict__ C) {
    constexpr int BM = MF * 32;          // 128 or 64
    constexpr int LDC = NB * 256;        // 4096 or 2048
    constexpr int APASS = BM / 64;       // glds passes for A tile (2 or 1)
    __attribute__((aligned(16))) __shared__ short lds[2][(BM + 256) * 64];
    const int tid = threadIdx.x;
    const int lane = tid & 63, wave = tid >> 6;
    const int quad = lane >> 4, l16 = lane & 15;
    const int wm = wave >> 2, wn = wave & 3;
    const int b = blockIdx.x;
    const int sw = (b & 7) * 32 + (b >> 3);   // XCD-bijective (256 % 8 == 0)
    const int n0 = (sw % NB) * 256;
    const int m0 = (sw / NB) * BM;
    const int lr = lane >> 3, lc = lane & 7;
    const int swc = lc ^ lr;             // pre-swizzled source chunk (involution)
    const int K = 4096;

    float4v acc[MF][4];
#pragma unroll
    for (int i = 0; i < MF; i++)
#pragma unroll
        for (int j = 0; j < 4; j++) acc[i][j] = (float4v){0.f, 0.f, 0.f, 0.f};

    auto stage = [&](int t, int buf) {
        const int k0 = t * 64;
        short* Ab = &lds[buf][0];
        short* Bb = &lds[buf][BM * 64];
#pragma unroll
        for (int p = 0; p < APASS; p++) {
            int row = p * 64 + wave * 8;  // wave-uniform LDS base row
            glds16(A + (size_t)(m0 + row + lr) * K + k0 + swc * 8, Ab + row * 64);
        }
#pragma unroll
        for (int p = 0; p < 4; p++) {
            int row = p * 64 + wave * 8;
            glds16(Bt + (size_t)(n0 + row + lr) * K + k0 + swc * 8, Bb + row * 64);
        }
    };

    stage(0, 0);
    stage(1, 1);

    for (int t = 0; t < 64; t++) {
        // tile t resident after waiting out all but next tile's loads
        if (t + 1 < 64) {
            if constexpr (APASS == 2) asm volatile("s_waitcnt vmcnt(6)" ::: "memory");
            else                      asm volatile("s_waitcnt vmcnt(5)" ::: "memory");
        } else {
            asm volatile("s_waitcnt vmcnt(0)" ::: "memory");
        }
        __builtin_amdgcn_sched_barrier(0);
        __builtin_amdgcn_s_barrier();
        asm volatile("" ::: "memory");
        const short* As = &lds[t & 1][0];
        const short* Bs = &lds[t & 1][BM * 64];
        short8 af[MF][2], bf[4][2];
#pragma unroll
        for (int mf = 0; mf < MF; mf++)
#pragma unroll
            for (int kc = 0; kc < 2; kc++)
                af[mf][kc] = *(const short8*)&As[(wm * MF * 16 + mf * 16 + l16) * 64 +
                                                 (((kc * 4 + quad) ^ (l16 & 7)) * 8)];
#pragma unroll
        for (int nf = 0; nf < 4; nf++)
#pragma unroll
            for (int kc = 0; kc < 2; kc++)
                bf[nf][kc] = *(const short8*)&Bs[(wn * 64 + nf * 16 + l16) * 64 +
                                                 (((kc * 4 + quad) ^ (l16 & 7)) * 8)];
        __builtin_amdgcn_s_setprio(1);
#pragma unroll
        for (int mf = 0; mf < MF; mf++)
#pragma unroll
            for (int nf = 0; nf < 4; nf++)
#pragma unroll
                for (int kc = 0; kc < 2; kc++)
                    acc[mf][nf] = __builtin_amdgcn_mfma_f32_16x16x32_bf16(
                        af[mf][kc], bf[nf][kc], acc[mf][nf], 0, 0, 0);
        __builtin_amdgcn_s_setprio(0);
        asm volatile("" ::: "memory");
        __builtin_amdgcn_s_barrier();   // all waves done reading buf[t&1]
        asm volatile("" ::: "memory");
        if (t + 2 < 64) stage(t + 2, t & 1);
    }

    // C layout: col = lane&15, row = quad*4 + reg
#pragma unroll
    for (int mf = 0; mf < MF; mf++)
#pragma unroll
        for (int nf = 0; nf < 4; nf++) {
            int col = n0 + wn * 64 + nf * 16 + l16;
#pragma unroll
            for (int r = 0; r < 4; r++) {
                int row = m0 + wm * MF * 16 + mf * 16 + quad * 4 + r;
                if constexpr (std::is_same<CT, float>::value)
                    C[(size_t)row * LDC + col] = acc[mf][nf][r];
                else
                    C[(size_t)row * LDC + col] = f2bf(acc[mf][nf][r]);
            }
        }
}

// ---------------------------------------------------------------------------
// GEMM (m97 structure): C(:, coff + [0,Nt)) = A (MxK) * Bt^T, Bt (Nt x K) bf16.
// 128x128 tile, BK=64, 4 waves 2x2. Used by fallback plans only.
// ---------------------------------------------------------------------------
template <typename AT, typename CT>
__global__ __launch_bounds__(256) void gemm_bt_g(const AT* __restrict__ A,
                                                 const short* __restrict__ Bt,
                                                 CT* __restrict__ C,
                                                 int K, int ldc, int coff) {
    __attribute__((aligned(16))) __shared__ short As[128 * 64];
    __attribute__((aligned(16))) __shared__ short Bs[128 * 64];
    const int tid = threadIdx.x;
    const int lane = tid & 63, wave = tid >> 6;
    const int quad = lane >> 4, l16 = lane & 15;
    const int wr = wave >> 1, wc = wave & 1;
    const int m0 = blockIdx.y * 128, n0 = blockIdx.x * 128;
    const int lrow = lane >> 3, lc8 = lane & 7;

    float4v acc[4][4];
#pragma unroll
    for (int i = 0; i < 4; i++)
#pragma unroll
        for (int j = 0; j < 4; j++) acc[i][j] = (float4v){0.f, 0.f, 0.f, 0.f};

    for (int k0 = 0; k0 < K; k0 += 64) {
#pragma unroll
        for (int r = 0; r < 4; r++) {
            int slab = r * 4 + wave;
            glds16(Bt + (size_t)(n0 + slab * 8 + lrow) * K + k0 + lc8 * 8, &Bs[slab * 512]);
        }
        if constexpr (std::is_same<AT, short>::value) {
#pragma unroll
            for (int r = 0; r < 4; r++) {
                int slab = r * 4 + wave;
                glds16(A + (size_t)(m0 + slab * 8 + lrow) * K + k0 + lc8 * 8, &As[slab * 512]);
            }
        } else {
#pragma unroll
            for (int i = 0; i < 4; i++) {
                int slot = tid + 256 * i;
                int row = slot >> 3, c8 = slot & 7;
                const float* src = A + (size_t)(m0 + row) * K + k0 + c8 * 8;
                float4v a = *(const float4v*)src;
                float4v b = *(const float4v*)(src + 4);
                short8 o;
#pragma unroll
                for (int j = 0; j < 4; j++) { o[j] = f2bf(a[j]); o[4 + j] = f2bf(b[j]); }
                *(short8*)&As[row * 64 + c8 * 8] = o;
            }
        }
        __syncthreads();
#pragma unroll
        for (int kc = 0; kc < 2; kc++) {
            short8 afr[4], bfr[4];
#pragma unroll
            for (int rt = 0; rt < 4; rt++)
                afr[rt] = *(const short8*)&As[(wr * 64 + rt * 16 + l16) * 64 + kc * 32 + quad * 8];
#pragma unroll
            for (int ct = 0; ct < 4; ct++)
                bfr[ct] = *(const short8*)&Bs[(wc * 64 + ct * 16 + l16) * 64 + kc * 32 + quad * 8];
#pragma unroll
            for (int rt = 0; rt < 4; rt++)
#pragma unroll
                for (int ct = 0; ct < 4; ct++)
                    acc[rt][ct] = __builtin_amdgcn_mfma_f32_16x16x32_bf16(
                        afr[rt], bfr[ct], acc[rt][ct], 0, 0, 0);
        }
        __syncthreads();
    }
#pragma unroll
    for (int rt = 0; rt < 4; rt++)
#pragma unroll
        for (int ct = 0; ct < 4; ct++) {
            int col = coff + n0 + wc * 64 + ct * 16 + l16;
#pragma unroll
            for (int r = 0; r < 4; r++) {
                int row = m0 + wr * 64 + rt * 16 + quad * 4 + r;
                if constexpr (std::is_same<CT, float>::value)
                    C[(size_t)row * ldc + col] = acc[rt][ct][r];
                else
                    C[(size_t)row * ldc + col] = f2bf(acc[rt][ct][r]);
            }
        }
}

// ---------------------------------------------------------------------------
// RoPE (interleaved pairs), in-place on (S, rows of ld) bf16; freqs f32.
// ---------------------------------------------------------------------------
__global__ void rope_kernel(short* __restrict__ T, const float* __restrict__ cosb,
                            const float* __restrict__ sinb, int nheads, int ld) {
    int idx = blockIdx.x * 256 + threadIdx.x;
    int total = 2048 * nheads * 16;
    if (idx >= total) return;
    int chunk = idx & 15;
    int t2 = idx >> 4;
    int hh = t2 % nheads;
    int s = t2 / nheads;
    short* p = T + (size_t)s * ld + hh * 128 + chunk * 8;
    short8 v = *(short8*)p;
    short8 o;
#pragma unroll
    for (int t = 0; t < 4; t++) {
        int i = chunk * 4 + t;
        float c = cosb[s * 64 + i];
        float sn = sinb[s * 64 + i];
        float a = bf2f(v[2 * t]), b = bf2f(v[2 * t + 1]);
        o[2 * t] = f2bf(a * c - b * sn);
        o[2 * t + 1] = f2bf(a * sn + b * c);
    }
    *(short8*)p = o;
}

// ---------------------------------------------------------------------------
// Flash attention v4 (= round-4 staging + exp2/T13 softmax):
// grid (16, 32); block does q-tiles {i, 31-i} -> exactly 33 KV iters at
// KVBLK=64. 4 waves x 16 q-rows. SINGLE K/V LDS buffer (41984 B -> 2
// blocks/CU; round-5 measured dbuf's 74752 B drops to 1 block/CU = -60%).
// Two __syncthreads/iter; reg prefetch of tile t+1 issued between them.
// XOR slot swizzle both sides. exp2-domain softmax, T13 defer-rescale.
// O may alias Q (block writes exactly the q rows it read).
// ---------------------------------------------------------------------------
__global__ __launch_bounds__(256) void attn_kernel(const short* __restrict__ Q,
                                                   const short* __restrict__ K,
                                                   const short* __restrict__ Vt,
                                                   short* __restrict__ O, int ldk) {
    __attribute__((aligned(16))) __shared__ short Ks[64 * 128];   // [kv][d] swizzled
    __attribute__((aligned(16))) __shared__ short Vs[128 * 64];   // [d][kv] swizzled
    __attribute__((aligned(16))) __shared__ short Ps[4][16 * 72];
    const int tid = threadIdx.x;
    const int lane = tid & 63, wave = tid >> 6;
    const int quad = lane >> 4, l16 = lane & 15;
    const int h = blockIdx.y, kvh = h >> 2;
    // scale * log2(e): softmax in exp2 domain
    const float scale2 = 0.08838834764831845f * 1.4426950408889634f;

    for (int pass = 0; pass < 2; pass++) {
        const int qtile = pass ? (31 - (int)blockIdx.x) : (int)blockIdx.x;
        const int qbase = qtile * 64;
        const int q0 = qbase + wave * 16;
        const int nt = qtile + 1;

        short8 qf[4];
        const short* qrow = Q + (size_t)(q0 + l16) * 4096 + h * 128;
#pragma unroll
        for (int ks = 0; ks < 4; ks++) qf[ks] = *(const short8*)(qrow + ks * 32 + quad * 8);

        float4v o_acc[8];
#pragma unroll
        for (int i = 0; i < 8; i++) o_acc[i] = (float4v){0.f, 0.f, 0.f, 0.f};
        float m_i[4], l_i[4];
#pragma unroll
        for (int r = 0; r < 4; r++) { m_i[r] = -1e9f; l_i[r] = 0.f; }

        // prologue: load tile 0 into regs
        short8 kreg[4], vreg[4];
#pragma unroll
        for (int i = 0; i < 4; i++) {
            int slot = tid + 256 * i;
            int row = slot >> 4, c8 = slot & 15;
            kreg[i] = *(const short8*)(K + (size_t)row * ldk + kvh * 128 + c8 * 8);
        }
#pragma unroll
        for (int i = 0; i < 4; i++) {
            int slot = tid + 256 * i;
            int row = slot >> 3, c8 = slot & 7;
            vreg[i] = *(const short8*)(Vt + (size_t)(kvh * 128 + row) * 2048 + c8 * 8);
        }

        for (int t = 0; t < nt; t++) {
            const int kv0 = t * 64;
            __syncthreads();  // all waves done reading LDS (prev iter / prev pass)
            // stage tile t: regs -> LDS (XOR slot swizzle)
#pragma unroll
            for (int i = 0; i < 4; i++) {
                int slot = tid + 256 * i;
                int row = slot >> 4, c8 = slot & 15;
                *(short8*)&Ks[row * 128 + ((c8 ^ (row & 15)) * 8)] = kreg[i];
            }
#pragma unroll
            for (int i = 0; i < 4; i++) {
                int slot = tid + 256 * i;
                int row = slot >> 3, c8 = slot & 7;
                *(short8*)&Vs[row * 64 + ((c8 ^ (row & 7)) * 8)] = vreg[i];
            }
            __syncthreads();  // staged data visible
            // prefetch tile t+1 (flies during compute below)
            if (t + 1 < nt) {
                const int kv1 = kv0 + 64;
#pragma unroll
                for (int i = 0; i < 4; i++) {
                    int slot = tid + 256 * i;
                    int row = slot >> 4, c8 = slot & 15;
                    kreg[i] = *(const short8*)(K + (size_t)(kv1 + row) * ldk + kvh * 128 + c8 * 8);
                }
#pragma unroll
                for (int i = 0; i < 4; i++) {
                    int slot = tid + 256 * i;
                    int row = slot >> 3, c8 = slot & 7;
                    vreg[i] = *(const short8*)(Vt + (size_t)(kvh * 128 + row) * 2048 + kv1 + c8 * 8);
                }
            }

            // ---- QK^T: 16 MFMA ----
            float4v s_acc[4];
#pragma unroll
            for (int i = 0; i < 4; i++) s_acc[i] = (float4v){0.f, 0.f, 0.f, 0.f};
            __builtin_amdgcn_s_setprio(1);
#pragma unroll
            for (int nsub = 0; nsub < 4; nsub++) {
                const int row = nsub * 16 + l16;  // row & 15 == l16
#pragma unroll
                for (int ks = 0; ks < 4; ks++) {
                    short8 kf = *(const short8*)&Ks[row * 128 + (((ks * 4 + quad) ^ l16) * 8)];
                    s_acc[nsub] = __builtin_amdgcn_mfma_f32_16x16x32_bf16(
                        qf[ks], kf, s_acc[nsub], 0, 0, 0);
                }
            }
            __builtin_amdgcn_s_setprio(0);

            // ---- online softmax (exp2 domain, T13 defer-rescale) ----
            const bool diag = (t == nt - 1);
            float p[4][4];
#pragma unroll
            for (int nsub = 0; nsub < 4; nsub++)
#pragma unroll
                for (int r = 0; r < 4; r++) {
                    float v = s_acc[nsub][r] * scale2;
                    if (diag) {
                        int rowq = q0 + quad * 4 + r;
                        int col = kv0 + nsub * 16 + l16;
                        v = (col <= rowq) ? v : -1e9f;
                    }
                    p[nsub][r] = v;
                }
            float tm[4];
#pragma unroll
            for (int r = 0; r < 4; r++)
                tm[r] = fmaxf(fmaxf(p[0][r], p[1][r]), fmaxf(p[2][r], p[3][r]));
#pragma unroll
            for (int off = 1; off < 16; off <<= 1)
#pragma unroll
                for (int r = 0; r < 4; r++)
                    tm[r] = fmaxf(tm[r], __shfl_xor(tm[r], off, 64));
            int ok = 1;
#pragma unroll
            for (int r = 0; r < 4; r++) ok &= (tm[r] <= m_i[r]);
            const bool need = !__all(ok);   // T13: rescale only if max grew
            float alpha[4];
            if (need) {
#pragma unroll
                for (int r = 0; r < 4; r++) {
                    float mn = fmaxf(m_i[r], tm[r]);
                    alpha[r] = __builtin_amdgcn_exp2f(m_i[r] - mn);
                    m_i[r] = mn;
                }
            }
            float rs[4];
#pragma unroll
            for (int r = 0; r < 4; r++) rs[r] = 0.f;
#pragma unroll
            for (int nsub = 0; nsub < 4; nsub++)
#pragma unroll
                for (int r = 0; r < 4; r++) {
                    float e = __builtin_amdgcn_exp2f(p[nsub][r] - m_i[r]);
                    rs[r] += e;
                    Ps[wave][(quad * 4 + r) * 72 + nsub * 16 + l16] = f2bf(e);
                }
#pragma unroll
            for (int off = 1; off < 16; off <<= 1)
#pragma unroll
                for (int r = 0; r < 4; r++) rs[r] += __shfl_xor(rs[r], off, 64);
            if (need) {
#pragma unroll
                for (int r = 0; r < 4; r++) l_i[r] = l_i[r] * alpha[r] + rs[r];
#pragma unroll
                for (int dt = 0; dt < 8; dt++)
#pragma unroll
                    for (int r = 0; r < 4; r++) o_acc[dt][r] *= alpha[r];
            } else {
#pragma unroll
                for (int r = 0; r < 4; r++) l_i[r] += rs[r];
            }

            // ---- PV: 16 MFMA ----
            short8 pf0 = *(const short8*)&Ps[wave][l16 * 72 + quad * 8];
            short8 pf1 = *(const short8*)&Ps[wave][l16 * 72 + 32 + quad * 8];
            __builtin_amdgcn_s_setprio(1);
#pragma unroll
            for (int dt = 0; dt < 8; dt++) {
                const int row = dt * 16 + l16;
                short8 vf0 = *(const short8*)&Vs[row * 64 + ((quad ^ (l16 & 7)) * 8)];
                short8 vf1 = *(const short8*)&Vs[row * 64 + (((4 + quad) ^ (l16 & 7)) * 8)];
                o_acc[dt] = __builtin_amdgcn_mfma_f32_16x16x32_bf16(pf0, vf0, o_acc[dt], 0, 0, 0);
                o_acc[dt] = __builtin_amdgcn_mfma_f32_16x16x32_bf16(pf1, vf1, o_acc[dt], 0, 0, 0);
            }
            __builtin_amdgcn_s_setprio(0);
        }

#pragma unroll
        for (int dt = 0; dt < 8; dt++)
#pragma unroll
            for (int r = 0; r < 4; r++) {
                int rowq = q0 + quad * 4 + r;
                O[(size_t)rowq * 4096 + h * 128 + dt * 16 + l16] = f2bf(o_acc[dt][r] / l_i[r]);
            }
    }
}

// ---------------------------------------------------------------------------
// Host. Workspace plans (adaptive on ws_size):
//  A (>=76MB): xb[0,16) Qb[16,32) KVb[32,40) Vt[40,44) WT[44,76)
//     Q/O proj: gemm_bt_p<4,16>; KV: gemm_bt_p<2,8> (all 256 blocks, 1/CU)
//  B (>=60MB): WT 16MB, Q/O proj in two N=2048 slices (old gemm)
//  C (else, 36MB): f32-A reg-staged gemms, 1024-col slices
// d_out is FLOAT32 (2048x4096 f32).
// ---------------------------------------------------------------------------
extern "C" void kernel_launch(void* const* d_in, const int* in_sizes, int n_in,
                              void* d_out, int out_size, void* d_ws, size_t ws_size,
                              hipStream_t stream) {
    (void)in_sizes; (void)n_in; (void)out_size;
    const float* x  = (const float*)d_in[0];
    const float* wq = (const float*)d_in[1];
    const float* wk = (const float*)d_in[2];
    const float* wv = (const float*)d_in[3];
    const float* wo = (const float*)d_in[4];
    const float* fc = (const float*)d_in[5];
    const float* fs = (const float*)d_in[6];
    float* out = (float*)d_out;
    char* ws = (char*)d_ws;
    const size_t MB = 1ull << 20;

    if (ws_size >= 76 * MB) {
        short* xb  = (short*)(ws);
        short* Qb  = (short*)(ws + 16 * MB);
        short* KVb = (short*)(ws + 32 * MB);
        short* Vt  = (short*)(ws + 40 * MB);
        short* WT  = (short*)(ws + 44 * MB);
        conv_f32_bf16<<<4096, 256, 0, stream>>>(x, xb, 2048 * 4096 / 8);
        transpose_conv<<<dim3(64, 64), 256, 0, stream>>>(wq, WT, 4096, 4096, 0);
        gemm_bt_p<4, 16, short><<<256, 512, 0, stream>>>(xb, WT, Qb);
        transpose_conv<<<dim3(16, 64), 256, 0, stream>>>(wk, WT, 4096, 1024, 0);
        transpose_conv<<<dim3(16, 64), 256, 0, stream>>>(wv, WT + (size_t)1024 * 4096, 4096, 1024, 0);
        gemm_bt_p<2, 8, short><<<256, 512, 0, stream>>>(xb, WT, KVb);
        rope_kernel<<<4096, 256, 0, stream>>>(Qb, fc, fs, 32, 4096);
        rope_kernel<<<1024, 256, 0, stream>>>(KVb, fc, fs, 8, 2048);
        transpose_k<<<dim3(16, 32), 256, 0, stream>>>(KVb + 1024, Vt, 2048, 1024, 2048);
        attn_kernel<<<dim3(16, 32), 256, 0, stream>>>(Qb, KVb, Vt, Qb, 2048);
        transpose_conv<<<dim3(64, 64), 256, 0, stream>>>(wo, WT, 4096, 4096, 0);
        gemm_bt_p<4, 16, float><<<256, 512, 0, stream>>>(Qb, WT, out);
    } else if (ws_size >= 60 * MB) {
        short* xb  = (short*)(ws);
        short* Qb  = (short*)(ws + 16 * MB);
        short* KVb = (short*)(ws + 32 * MB);
        short* Vt  = (short*)(ws + 40 * MB);
        short* WT  = (short*)(ws + 44 * MB);
        conv_f32_bf16<<<4096, 256, 0, stream>>>(x, xb, 2048 * 4096 / 8);
        for (int s = 0; s < 2; s++) {
            transpose_conv<<<dim3(32, 64), 256, 0, stream>>>(wq, WT, 4096, 4096, s * 2048);
            gemm_bt_g<short, short><<<dim3(16, 16), 256, 0, stream>>>(xb, WT, Qb, 4096, 4096, s * 2048);
        }
        transpose_conv<<<dim3(16, 64), 256, 0, stream>>>(wk, WT, 4096, 1024, 0);
        transpose_conv<<<dim3(16, 64), 256, 0, stream>>>(wv, WT + (size_t)1024 * 4096, 4096, 1024, 0);
        gemm_bt_g<short, short><<<dim3(16, 16), 256, 0, stream>>>(xb, WT, KVb, 4096, 2048, 0);
        rope_kernel<<<4096, 256, 0, stream>>>(Qb, fc, fs, 32, 4096);
        rope_kernel<<<1024, 256, 0, stream>>>(KVb, fc, fs, 8, 2048);
        transpose_k<<<dim3(16, 32), 256, 0, stream>>>(KVb + 1024, Vt, 2048, 1024, 2048);
        attn_kernel<<<dim3(16, 32), 256, 0, stream>>>(Qb, KVb, Vt, Qb, 2048);
        for (int s = 0; s < 2; s++) {
            transpose_conv<<<dim3(32, 64), 256, 0, stream>>>(wo, WT, 4096, 4096, s * 2048);
            gemm_bt_g<short, float><<<dim3(16, 16), 256, 0, stream>>>(Qb, WT, out, 4096, 4096, s * 2048);
        }
    } else {
        short* WT = (short*)(ws);
        short* Qb = (short*)(ws + 8 * MB);
        short* Kb = (short*)(ws + 24 * MB);
        short* Vb = (short*)(ws + 28 * MB);
        short* Vt = (short*)(ws + 32 * MB);
        for (int s = 0; s < 4; s++) {
            transpose_conv<<<dim3(16, 64), 256, 0, stream>>>(wq, WT, 4096, 4096, s * 1024);
            gemm_bt_g<float, short><<<dim3(8, 16), 256, 0, stream>>>(x, WT, Qb, 4096, 4096, s * 1024);
        }
        transpose_conv<<<dim3(16, 64), 256, 0, stream>>>(wk, WT, 4096, 1024, 0);
        gemm_bt_g<float, short><<<dim3(8, 16), 256, 0, stream>>>(x, WT, Kb, 4096, 1024, 0);
        transpose_conv<<<dim3(16, 64), 256, 0, stream>>>(wv, WT, 4096, 1024, 0);
        gemm_bt_g<float, short><<<dim3(8, 16), 256, 0, stream>>>(x, WT, Vb, 4096, 1024, 0);
        rope_kernel<<<4096, 256, 0, stream>>>(Qb, fc, fs, 32, 4096);
        rope_kernel<<<1024, 256, 0, stream>>>(Kb, fc, fs, 8, 1024);
        transpose_k<<<dim3(16, 32), 256, 0, stream>>>(Vb, Vt, 2048, 1024, 1024);
        attn_kernel<<<dim3(16, 32), 256, 0, stream>>>(Qb, Kb, Vt, Qb, 1024);
        for (int s = 0; s < 4; s++) {
            transpose_conv<<<dim3(16, 64), 256, 0, stream>>>(wo, WT, 4096, 4096, s * 1024);
            gemm_bt_g<short, float><<<dim3(8, 16), 256, 0, stream>>>(Qb, WT, out, 4096, 4096, s * 1024);
        }
    }
}

// Round 7
// 505.338 us; speedup vs baseline: 1.1229x; 1.1155x over previous
//
#include <hip/hip_runtime.h>
#include <type_traits>

typedef __attribute__((ext_vector_type(8))) short short8;
typedef __attribute__((ext_vector_type(4))) float float4v;

__device__ inline float bf2f(short s) {
    unsigned u = ((unsigned)(unsigned short)s) << 16;
    float f; __builtin_memcpy(&f, &u, 4); return f;
}
__device__ inline short f2bf(float f) {
    unsigned u; __builtin_memcpy(&u, &f, 4);
    unsigned lsb = (u >> 16) & 1;
    u += 0x7fffu + lsb;
    return (short)(u >> 16);
}

// async global->LDS, 16B per lane; lds dest must be wave-uniform base (HW adds lane*16)
__device__ inline void glds16(const void* g, void* l) {
    __builtin_amdgcn_global_load_lds(
        (const __attribute__((address_space(1))) unsigned int*)g,
        (__attribute__((address_space(3))) unsigned int*)l, 16, 0, 0);
}

// ---------------------------------------------------------------------------
// f32 -> bf16 elementwise (x pre-conversion). 8 elems/thread.
// ---------------------------------------------------------------------------
__global__ __launch_bounds__(256) void conv_f32_bf16(const float* __restrict__ in,
                                                     short* __restrict__ out, int n8) {
    int idx = blockIdx.x * 256 + threadIdx.x;
    if (idx >= n8) return;
    const float* src = in + (size_t)idx * 8;
    float4v a = *(const float4v*)src;
    float4v b = *(const float4v*)(src + 4);
    short8 o;
#pragma unroll
    for (int j = 0; j < 4; j++) { o[j] = f2bf(a[j]); o[4 + j] = f2bf(b[j]); }
    *(short8*)(out + (size_t)idx * 8) = o;
}

// ---------------------------------------------------------------------------
// Transpose + convert: in f32 (K x ldn), column slice [noff, noff+Ntile) ->
// out bf16 (Ntile x K). 64x64 tiles.
// ---------------------------------------------------------------------------
__global__ __launch_bounds__(256) void transpose_conv(const float* __restrict__ in,
                                                      short* __restrict__ out,
                                                      int K, int ldn, int noff) {
    __shared__ float t[64 * 65];
    const int n0 = blockIdx.x * 64, k0 = blockIdx.y * 64;
    const int tid = threadIdx.x;
#pragma unroll
    for (int i = 0; i < 4; i++) {
        int slot = tid + 256 * i;
        int row = slot >> 4, c4 = slot & 15;
        float4v v = *(const float4v*)(in + (size_t)(k0 + row) * ldn + noff + n0 + c4 * 4);
#pragma unroll
        for (int j = 0; j < 4; j++) t[row * 65 + c4 * 4 + j] = v[j];
    }
    __syncthreads();
#pragma unroll
    for (int i = 0; i < 2; i++) {
        int slot = tid + 256 * i;
        int row = slot >> 3, c8 = slot & 7;
        short8 v;
#pragma unroll
        for (int j = 0; j < 8; j++) v[j] = f2bf(t[(c8 * 8 + j) * 65 + row]);
        *(short8*)(out + (size_t)(n0 + row) * K + k0 + c8 * 8) = v;
    }
}

// ---------------------------------------------------------------------------
// bf16 transpose: in (K x N, row stride ldin) -> out (N x K), 64x64 tiles
// ---------------------------------------------------------------------------
__global__ __launch_bounds__(256) void transpose_k(const short* __restrict__ in,
                                                   short* __restrict__ out,
                                                   int K, int N, int ldin) {
    __attribute__((aligned(16))) __shared__ short t[64 * 72];
    const int n0 = blockIdx.x * 64, k0 = blockIdx.y * 64;
    const int tid = threadIdx.x;
#pragma unroll
    for (int i = 0; i < 2; i++) {
        int slot = tid + 256 * i;
        int row = slot >> 3, c8 = slot & 7;
        *(short8*)&t[row * 72 + c8 * 8] =
            *(const short8*)(in + (size_t)(k0 + row) * ldin + n0 + c8 * 8);
    }
    __syncthreads();
#pragma unroll
    for (int i = 0; i < 2; i++) {
        int slot = tid + 256 * i;
        int row = slot >> 3, c8 = slot & 7;
        short8 v;
#pragma unroll
        for (int j = 0; j < 8; j++) v[j] = t[(c8 * 8 + j) * 72 + row];
        *(short8*)(out + (size_t)(n0 + row) * K + k0 + c8 * 8) = v;
    }
}

// ---------------------------------------------------------------------------
// Deep-pipelined GEMM, templated tile: C = A (2048 x 4096 bf16) * Bt^T.
// MF = m-frags/wave (4 -> BM=128, 2 -> BM=64); NB = N/256 n-blocks.
// 8 waves (2M x 4N); per-wave MF*16 x 64 output. Grid: 256 blocks (1/CU),
// XCD-bijective swizzle. LDS: 2 x (BM+256) x 64 bf16 double buffer.
// Staging via global_load_lds w16, 2-tile lookahead, counted vmcnt at loop
// top (never drains in steady state), raw s_barrier. T2 chunk-XOR swizzle
// via pre-swizzled global source + swizzled ds_read (same involution).
// Hang-safety: all staged addresses in-bounds for every t; uniform barriers.
// ---------------------------------------------------------------------------
template <int MF, int NB, typename CT>
__global__ __launch_bounds__(512) void gemm_bt_p(const short* __restrict__ A,
                                                 const short* __restrict__ Bt,
                                                 CT* __restrict__ C) {
    constexpr int BM = MF * 32;          // 128 or 64
    constexpr int LDC = NB * 256;        // 4096 or 2048
    constexpr int APASS = BM / 64;       // glds passes for A tile (2 or 1)
    __attribute__((aligned(16))) __shared__ short lds[2][(BM + 256) * 64];
    const int tid = threadIdx.x;
    const int lane = tid & 63, wave = tid >> 6;
    const int quad = lane >> 4, l16 = lane & 15;
    const int wm = wave >> 2, wn = wave & 3;
    const int b = blockIdx.x;
    const int sw = (b & 7) * 32 + (b >> 3);   // XCD-bijective (256 % 8 == 0)
    const int n0 = (sw % NB) * 256;
    const int m0 = (sw / NB) * BM;
    const int lr = lane >> 3, lc = lane & 7;
    const int swc = lc ^ lr;             // pre-swizzled source chunk (involution)
    const int K = 4096;

    float4v acc[MF][4];
#pragma unroll
    for (int i = 0; i < MF; i++)
#pragma unroll
        for (int j = 0; j < 4; j++) acc[i][j] = (float4v){0.f, 0.f, 0.f, 0.f};

    auto stage = [&](int t, int buf) {
        const int k0 = t * 64;
        short* Ab = &lds[buf][0];
        short* Bb = &lds[buf][BM * 64];
#pragma unroll
        for (int p = 0; p < APASS; p++) {
            int row = p * 64 + wave * 8;  // wave-uniform LDS base row
            glds16(A + (size_t)(m0 + row + lr) * K + k0 + swc * 8, Ab + row * 64);
        }
#pragma unroll
        for (int p = 0; p < 4; p++) {
            int row = p * 64 + wave * 8;
            glds16(Bt + (size_t)(n0 + row + lr) * K + k0 + swc * 8, Bb + row * 64);
        }
    };

    stage(0, 0);
    stage(1, 1);

    for (int t = 0; t < 64; t++) {
        // tile t resident after waiting out all but next tile's loads
        if (t + 1 < 64) {
            if constexpr (APASS == 2) asm volatile("s_waitcnt vmcnt(6)" ::: "memory");
            else                      asm volatile("s_waitcnt vmcnt(5)" ::: "memory");
        } else {
            asm volatile("s_waitcnt vmcnt(0)" ::: "memory");
        }
        __builtin_amdgcn_sched_barrier(0);
        __builtin_amdgcn_s_barrier();
        asm volatile("" ::: "memory");
        const short* As = &lds[t & 1][0];
        const short* Bs = &lds[t & 1][BM * 64];
        short8 af[MF][2], bf[4][2];
#pragma unroll
        for (int mf = 0; mf < MF; mf++)
#pragma unroll
            for (int kc = 0; kc < 2; kc++)
                af[mf][kc] = *(const short8*)&As[(wm * MF * 16 + mf * 16 + l16) * 64 +
                                                 (((kc * 4 + quad) ^ (l16 & 7)) * 8)];
#pragma unroll
        for (int nf = 0; nf < 4; nf++)
#pragma unroll
            for (int kc = 0; kc < 2; kc++)
                bf[nf][kc] = *(const short8*)&Bs[(wn * 64 + nf * 16 + l16) * 64 +
                                                 (((kc * 4 + quad) ^ (l16 & 7)) * 8)];
        __builtin_amdgcn_s_setprio(1);
#pragma unroll
        for (int mf = 0; mf < MF; mf++)
#pragma unroll
            for (int nf = 0; nf < 4; nf++)
#pragma unroll
                for (int kc = 0; kc < 2; kc++)
                    acc[mf][nf] = __builtin_amdgcn_mfma_f32_16x16x32_bf16(
                        af[mf][kc], bf[nf][kc], acc[mf][nf], 0, 0, 0);
        __builtin_amdgcn_s_setprio(0);
        asm volatile("" ::: "memory");
        __builtin_amdgcn_s_barrier();   // all waves done reading buf[t&1]
        asm volatile("" ::: "memory");
        if (t + 2 < 64) stage(t + 2, t & 1);
    }

    // C layout: col = lane&15, row = quad*4 + reg
#pragma unroll
    for (int mf = 0; mf < MF; mf++)
#pragma unroll
        for (int nf = 0; nf < 4; nf++) {
            int col = n0 + wn * 64 + nf * 16 + l16;
#pragma unroll
            for (int r = 0; r < 4; r++) {
                int row = m0 + wm * MF * 16 + mf * 16 + quad * 4 + r;
                if constexpr (std::is_same<CT, float>::value)
                    C[(size_t)row * LDC + col] = acc[mf][nf][r];
                else
                    C[(size_t)row * LDC + col] = f2bf(acc[mf][nf][r]);
            }
        }
}

// ---------------------------------------------------------------------------
// GEMM (m97 structure): C(:, coff + [0,Nt)) = A (MxK) * Bt^T, Bt (Nt x K) bf16.
// 128x128 tile, BK=64, 4 waves 2x2. Used by fallback plans only.
// ---------------------------------------------------------------------------
template <typename AT, typename CT>
__global__ __launch_bounds__(256) void gemm_bt_g(const AT* __restrict__ A,
                                                 const short* __restrict__ Bt,
                                                 CT* __restrict__ C,
                                                 int K, int ldc, int coff) {
    __attribute__((aligned(16))) __shared__ short As[128 * 64];
    __attribute__((aligned(16))) __shared__ short Bs[128 * 64];
    const int tid = threadIdx.x;
    const int lane = tid & 63, wave = tid >> 6;
    const int quad = lane >> 4, l16 = lane & 15;
    const int wr = wave >> 1, wc = wave & 1;
    const int m0 = blockIdx.y * 128, n0 = blockIdx.x * 128;
    const int lrow = lane >> 3, lc8 = lane & 7;

    float4v acc[4][4];
#pragma unroll
    for (int i = 0; i < 4; i++)
#pragma unroll
        for (int j = 0; j < 4; j++) acc[i][j] = (float4v){0.f, 0.f, 0.f, 0.f};

    for (int k0 = 0; k0 < K; k0 += 64) {
#pragma unroll
        for (int r = 0; r < 4; r++) {
            int slab = r * 4 + wave;
            glds16(Bt + (size_t)(n0 + slab * 8 + lrow) * K + k0 + lc8 * 8, &Bs[slab * 512]);
        }
        if constexpr (std::is_same<AT, short>::value) {
#pragma unroll
            for (int r = 0; r < 4; r++) {
                int slab = r * 4 + wave;
                glds16(A + (size_t)(m0 + slab * 8 + lrow) * K + k0 + lc8 * 8, &As[slab * 512]);
            }
        } else {
#pragma unroll
            for (int i = 0; i < 4; i++) {
                int slot = tid + 256 * i;
                int row = slot >> 3, c8 = slot & 7;
                const float* src = A + (size_t)(m0 + row) * K + k0 + c8 * 8;
                float4v a = *(const float4v*)src;
                float4v b = *(const float4v*)(src + 4);
                short8 o;
#pragma unroll
                for (int j = 0; j < 4; j++) { o[j] = f2bf(a[j]); o[4 + j] = f2bf(b[j]); }
                *(short8*)&As[row * 64 + c8 * 8] = o;
            }
        }
        __syncthreads();
#pragma unroll
        for (int kc = 0; kc < 2; kc++) {
            short8 afr[4], bfr[4];
#pragma unroll
            for (int rt = 0; rt < 4; rt++)
                afr[rt] = *(const short8*)&As[(wr * 64 + rt * 16 + l16) * 64 + kc * 32 + quad * 8];
#pragma unroll
            for (int ct = 0; ct < 4; ct++)
                bfr[ct] = *(const short8*)&Bs[(wc * 64 + ct * 16 + l16) * 64 + kc * 32 + quad * 8];
#pragma unroll
            for (int rt = 0; rt < 4; rt++)
#pragma unroll
                for (int ct = 0; ct < 4; ct++)
                    acc[rt][ct] = __builtin_amdgcn_mfma_f32_16x16x32_bf16(
                        afr[rt], bfr[ct], acc[rt][ct], 0, 0, 0);
        }
        __syncthreads();
    }
#pragma unroll
    for (int rt = 0; rt < 4; rt++)
#pragma unroll
        for (int ct = 0; ct < 4; ct++) {
            int col = coff + n0 + wc * 64 + ct * 16 + l16;
#pragma unroll
            for (int r = 0; r < 4; r++) {
                int row = m0 + wr * 64 + rt * 16 + quad * 4 + r;
                if constexpr (std::is_same<CT, float>::value)
                    C[(size_t)row * ldc + col] = acc[rt][ct][r];
                else
                    C[(size_t)row * ldc + col] = f2bf(acc[rt][ct][r]);
            }
        }
}

// ---------------------------------------------------------------------------
// RoPE (interleaved pairs), in-place on (S, rows of ld) bf16; freqs f32.
// ---------------------------------------------------------------------------
__global__ void rope_kernel(short* __restrict__ T, const float* __restrict__ cosb,
                            const float* __restrict__ sinb, int nheads, int ld) {
    int idx = blockIdx.x * 256 + threadIdx.x;
    int total = 2048 * nheads * 16;
    if (idx >= total) return;
    int chunk = idx & 15;
    int t2 = idx >> 4;
    int hh = t2 % nheads;
    int s = t2 / nheads;
    short* p = T + (size_t)s * ld + hh * 128 + chunk * 8;
    short8 v = *(short8*)p;
    short8 o;
#pragma unroll
    for (int t = 0; t < 4; t++) {
        int i = chunk * 4 + t;
        float c = cosb[s * 64 + i];
        float sn = sinb[s * 64 + i];
        float a = bf2f(v[2 * t]), b = bf2f(v[2 * t + 1]);
        o[2 * t] = f2bf(a * c - b * sn);
        o[2 * t + 1] = f2bf(a * sn + b * c);
    }
    *(short8*)p = o;
}

// ---------------------------------------------------------------------------
// Flash attention v5 = round-4 structure + exp2 softmax, VGPR-pinned.
// grid (16, 32); block does q-tiles {i, 31-i} -> exactly 33 KV iters at
// KVBLK=64. 4 waves x 16 q-rows. Single K/V LDS buffer (41984 B).
// __launch_bounds__(256, 4) pins VGPR <= 128: round-6 measured VGPR=132
// (cliff at 128, m69) halves residency -> 158 us vs 102 us at VGPR=120.
// No T13 (its branch state caused the VGPR spill past 128).
// Two __syncthreads/iter; reg prefetch of tile t+1 between them.
// XOR slot swizzle both sides. O may alias Q.
// ---------------------------------------------------------------------------
__global__ __launch_bounds__(256, 4) void attn_kernel(const short* __restrict__ Q,
                                                      const short* __restrict__ K,
                                                      const short* __restrict__ Vt,
                                                      short* __restrict__ O, int ldk) {
    __attribute__((aligned(16))) __shared__ short Ks[64 * 128];   // [kv][d] swizzled
    __attribute__((aligned(16))) __shared__ short Vs[128 * 64];   // [d][kv] swizzled
    __attribute__((aligned(16))) __shared__ short Ps[4][16 * 72];
    const int tid = threadIdx.x;
    const int lane = tid & 63, wave = tid >> 6;
    const int quad = lane >> 4, l16 = lane & 15;
    const int h = blockIdx.y, kvh = h >> 2;
    // scale * log2(e): softmax in exp2 domain
    const float scale2 = 0.08838834764831845f * 1.4426950408889634f;

    for (int pass = 0; pass < 2; pass++) {
        const int qtile = pass ? (31 - (int)blockIdx.x) : (int)blockIdx.x;
        const int qbase = qtile * 64;
        const int q0 = qbase + wave * 16;
        const int nt = qtile + 1;

        short8 qf[4];
        const short* qrow = Q + (size_t)(q0 + l16) * 4096 + h * 128;
#pragma unroll
        for (int ks = 0; ks < 4; ks++) qf[ks] = *(const short8*)(qrow + ks * 32 + quad * 8);

        float4v o_acc[8];
#pragma unroll
        for (int i = 0; i < 8; i++) o_acc[i] = (float4v){0.f, 0.f, 0.f, 0.f};
        float m_i[4], l_i[4];
#pragma unroll
        for (int r = 0; r < 4; r++) { m_i[r] = -1e9f; l_i[r] = 0.f; }

        // prologue: load tile 0 into regs
        short8 kreg[4], vreg[4];
#pragma unroll
        for (int i = 0; i < 4; i++) {
            int slot = tid + 256 * i;
            int row = slot >> 4, c8 = slot & 15;
            kreg[i] = *(const short8*)(K + (size_t)row * ldk + kvh * 128 + c8 * 8);
        }
#pragma unroll
        for (int i = 0; i < 4; i++) {
            int slot = tid + 256 * i;
            int row = slot >> 3, c8 = slot & 7;
            vreg[i] = *(const short8*)(Vt + (size_t)(kvh * 128 + row) * 2048 + c8 * 8);
        }

        for (int t = 0; t < nt; t++) {
            const int kv0 = t * 64;
            __syncthreads();  // all waves done reading LDS (prev iter / prev pass)
            // stage tile t: regs -> LDS (XOR slot swizzle)
#pragma unroll
            for (int i = 0; i < 4; i++) {
                int slot = tid + 256 * i;
                int row = slot >> 4, c8 = slot & 15;
                *(short8*)&Ks[row * 128 + ((c8 ^ (row & 15)) * 8)] = kreg[i];
            }
#pragma unroll
            for (int i = 0; i < 4; i++) {
                int slot = tid + 256 * i;
                int row = slot >> 3, c8 = slot & 7;
                *(short8*)&Vs[row * 64 + ((c8 ^ (row & 7)) * 8)] = vreg[i];
            }
            __syncthreads();  // staged data visible
            // prefetch tile t+1 (flies during compute below)
            if (t + 1 < nt) {
                const int kv1 = kv0 + 64;
#pragma unroll
                for (int i = 0; i < 4; i++) {
                    int slot = tid + 256 * i;
                    int row = slot >> 4, c8 = slot & 15;
                    kreg[i] = *(const short8*)(K + (size_t)(kv1 + row) * ldk + kvh * 128 + c8 * 8);
                }
#pragma unroll
                for (int i = 0; i < 4; i++) {
                    int slot = tid + 256 * i;
                    int row = slot >> 3, c8 = slot & 7;
                    vreg[i] = *(const short8*)(Vt + (size_t)(kvh * 128 + row) * 2048 + kv1 + c8 * 8);
                }
            }

            // ---- QK^T: 16 MFMA ----
            float4v s_acc[4];
#pragma unroll
            for (int i = 0; i < 4; i++) s_acc[i] = (float4v){0.f, 0.f, 0.f, 0.f};
            __builtin_amdgcn_s_setprio(1);
#pragma unroll
            for (int nsub = 0; nsub < 4; nsub++) {
                const int row = nsub * 16 + l16;  // row & 15 == l16
#pragma unroll
                for (int ks = 0; ks < 4; ks++) {
                    short8 kf = *(const short8*)&Ks[row * 128 + (((ks * 4 + quad) ^ l16) * 8)];
                    s_acc[nsub] = __builtin_amdgcn_mfma_f32_16x16x32_bf16(
                        qf[ks], kf, s_acc[nsub], 0, 0, 0);
                }
            }
            __builtin_amdgcn_s_setprio(0);

            // ---- online softmax (exp2 domain, always-rescale) ----
            const bool diag = (t == nt - 1);
            float p[4][4];
#pragma unroll
            for (int nsub = 0; nsub < 4; nsub++)
#pragma unroll
                for (int r = 0; r < 4; r++) {
                    float v = s_acc[nsub][r] * scale2;
                    if (diag) {
                        int rowq = q0 + quad * 4 + r;
                        int col = kv0 + nsub * 16 + l16;
                        v = (col <= rowq) ? v : -1e9f;
                    }
                    p[nsub][r] = v;
                }
            float tm[4];
#pragma unroll
            for (int r = 0; r < 4; r++)
                tm[r] = fmaxf(fmaxf(p[0][r], p[1][r]), fmaxf(p[2][r], p[3][r]));
#pragma unroll
            for (int off = 1; off < 16; off <<= 1)
#pragma unroll
                for (int r = 0; r < 4; r++)
                    tm[r] = fmaxf(tm[r], __shfl_xor(tm[r], off, 64));
            float alpha[4], rs[4];
#pragma unroll
            for (int r = 0; r < 4; r++) {
                float mn = fmaxf(m_i[r], tm[r]);
                alpha[r] = __builtin_amdgcn_exp2f(m_i[r] - mn);
                m_i[r] = mn;
                rs[r] = 0.f;
            }
#pragma unroll
            for (int nsub = 0; nsub < 4; nsub++)
#pragma unroll
                for (int r = 0; r < 4; r++) {
                    float e = __builtin_amdgcn_exp2f(p[nsub][r] - m_i[r]);
                    rs[r] += e;
                    Ps[wave][(quad * 4 + r) * 72 + nsub * 16 + l16] = f2bf(e);
                }
#pragma unroll
            for (int off = 1; off < 16; off <<= 1)
#pragma unroll
                for (int r = 0; r < 4; r++) rs[r] += __shfl_xor(rs[r], off, 64);
#pragma unroll
            for (int r = 0; r < 4; r++) l_i[r] = l_i[r] * alpha[r] + rs[r];
#pragma unroll
            for (int dt = 0; dt < 8; dt++)
#pragma unroll
                for (int r = 0; r < 4; r++) o_acc[dt][r] *= alpha[r];

            // ---- PV: 16 MFMA ----
            short8 pf0 = *(const short8*)&Ps[wave][l16 * 72 + quad * 8];
            short8 pf1 = *(const short8*)&Ps[wave][l16 * 72 + 32 + quad * 8];
            __builtin_amdgcn_s_setprio(1);
#pragma unroll
            for (int dt = 0; dt < 8; dt++) {
                const int row = dt * 16 + l16;
                short8 vf0 = *(const short8*)&Vs[row * 64 + ((quad ^ (l16 & 7)) * 8)];
                short8 vf1 = *(const short8*)&Vs[row * 64 + (((4 + quad) ^ (l16 & 7)) * 8)];
                o_acc[dt] = __builtin_amdgcn_mfma_f32_16x16x32_bf16(pf0, vf0, o_acc[dt], 0, 0, 0);
                o_acc[dt] = __builtin_amdgcn_mfma_f32_16x16x32_bf16(pf1, vf1, o_acc[dt], 0, 0, 0);
            }
            __builtin_amdgcn_s_setprio(0);
        }

#pragma unroll
        for (int dt = 0; dt < 8; dt++)
#pragma unroll
            for (int r = 0; r < 4; r++) {
                int rowq = q0 + quad * 4 + r;
                O[(size_t)rowq * 4096 + h * 128 + dt * 16 + l16] = f2bf(o_acc[dt][r] / l_i[r]);
            }
    }
}

// ---------------------------------------------------------------------------
// Host. Workspace plans (adaptive on ws_size):
//  A (>=76MB): xb[0,16) Qb[16,32) KVb[32,40) Vt[40,44) WT[44,76)
//     Q/O proj: gemm_bt_p<4,16>; KV: gemm_bt_p<2,8> (all 256 blocks, 1/CU)
//  B (>=60MB): WT 16MB, Q/O proj in two N=2048 slices (old gemm)
//  C (else, 36MB): f32-A reg-staged gemms, 1024-col slices
// d_out is FLOAT32 (2048x4096 f32).
// ---------------------------------------------------------------------------
extern "C" void kernel_launch(void* const* d_in, const int* in_sizes, int n_in,
                              void* d_out, int out_size, void* d_ws, size_t ws_size,
                              hipStream_t stream) {
    (void)in_sizes; (void)n_in; (void)out_size;
    const float* x  = (const float*)d_in[0];
    const float* wq = (const float*)d_in[1];
    const float* wk = (const float*)d_in[2];
    const float* wv = (const float*)d_in[3];
    const float* wo = (const float*)d_in[4];
    const float* fc = (const float*)d_in[5];
    const float* fs = (const float*)d_in[6];
    float* out = (float*)d_out;
    char* ws = (char*)d_ws;
    const size_t MB = 1ull << 20;

    if (ws_size >= 76 * MB) {
        short* xb  = (short*)(ws);
        short* Qb  = (short*)(ws + 16 * MB);
        short* KVb = (short*)(ws + 32 * MB);
        short* Vt  = (short*)(ws + 40 * MB);
        short* WT  = (short*)(ws + 44 * MB);
        conv_f32_bf16<<<4096, 256, 0, stream>>>(x, xb, 2048 * 4096 / 8);
        transpose_conv<<<dim3(64, 64), 256, 0, stream>>>(wq, WT, 4096, 4096, 0);
        gemm_bt_p<4, 16, short><<<256, 512, 0, stream>>>(xb, WT, Qb);
        transpose_conv<<<dim3(16, 64), 256, 0, stream>>>(wk, WT, 4096, 1024, 0);
        transpose_conv<<<dim3(16, 64), 256, 0, stream>>>(wv, WT + (size_t)1024 * 4096, 4096, 1024, 0);
        gemm_bt_p<2, 8, short><<<256, 512, 0, stream>>>(xb, WT, KVb);
        rope_kernel<<<4096, 256, 0, stream>>>(Qb, fc, fs, 32, 4096);
        rope_kernel<<<1024, 256, 0, stream>>>(KVb, fc, fs, 8, 2048);
        transpose_k<<<dim3(16, 32), 256, 0, stream>>>(KVb + 1024, Vt, 2048, 1024, 2048);
        attn_kernel<<<dim3(16, 32), 256, 0, stream>>>(Qb, KVb, Vt, Qb, 2048);
        transpose_conv<<<dim3(64, 64), 256, 0, stream>>>(wo, WT, 4096, 4096, 0);
        gemm_bt_p<4, 16, float><<<256, 512, 0, stream>>>(Qb, WT, out);
    } else if (ws_size >= 60 * MB) {
        short* xb  = (short*)(ws);
        short* Qb  = (short*)(ws + 16 * MB);
        short* KVb = (short*)(ws + 32 * MB);
        short* Vt  = (short*)(ws + 40 * MB);
        short* WT  = (short*)(ws + 44 * MB);
        conv_f32_bf16<<<4096, 256, 0, stream>>>(x, xb, 2048 * 4096 / 8);
        for (int s = 0; s < 2; s++) {
            transpose_conv<<<dim3(32, 64), 256, 0, stream>>>(wq, WT, 4096, 4096, s * 2048);
            gemm_bt_g<short, short><<<dim3(16, 16), 256, 0, stream>>>(xb, WT, Qb, 4096, 4096, s * 2048);
        }
        transpose_conv<<<dim3(16, 64), 256, 0, stream>>>(wk, WT, 4096, 1024, 0);
        transpose_conv<<<dim3(16, 64), 256, 0, stream>>>(wv, WT + (size_t)1024 * 4096, 4096, 1024, 0);
        gemm_bt_g<short, short><<<dim3(16, 16), 256, 0, stream>>>(xb, WT, KVb, 4096, 2048, 0);
        rope_kernel<<<4096, 256, 0, stream>>>(Qb, fc, fs, 32, 4096);
        rope_kernel<<<1024, 256, 0, stream>>>(KVb, fc, fs, 8, 2048);
        transpose_k<<<dim3(16, 32), 256, 0, stream>>>(KVb + 1024, Vt, 2048, 1024, 2048);
        attn_kernel<<<dim3(16, 32), 256, 0, stream>>>(Qb, KVb, Vt, Qb, 2048);
        for (int s = 0; s < 2; s++) {
            transpose_conv<<<dim3(32, 64), 256, 0, stream>>>(wo, WT, 4096, 4096, s * 2048);
            gemm_bt_g<short, float><<<dim3(16, 16), 256, 0, stream>>>(Qb, WT, out, 4096, 4096, s * 2048);
        }
    } else {
        short* WT = (short*)(ws);
        short* Qb = (short*)(ws + 8 * MB);
        short* Kb = (short*)(ws + 24 * MB);
        short* Vb = (short*)(ws + 28 * MB);
        short* Vt = (short*)(ws + 32 * MB);
        for (int s = 0; s < 4; s++) {
            transpose_conv<<<dim3(16, 64), 256, 0, stream>>>(wq, WT, 4096, 4096, s * 1024);
            gemm_bt_g<float, short><<<dim3(8, 16), 256, 0, stream>>>(x, WT, Qb, 4096, 4096, s * 1024);
        }
        transpose_conv<<<dim3(16, 64), 256, 0, stream>>>(wk, WT, 4096, 1024, 0);
        gemm_bt_g<float, short><<<dim3(8, 16), 256, 0, stream>>>(x, WT, Kb, 4096, 1024, 0);
        transpose_conv<<<dim3(16, 64), 256, 0, stream>>>(wv, WT, 4096, 1024, 0);
        gemm_bt_g<float, short><<<dim3(8, 16), 256, 0, stream>>>(x, WT, Vb, 4096, 1024, 0);
        rope_kernel<<<4096, 256, 0, stream>>>(Qb, fc, fs, 32, 4096);
        rope_kernel<<<1024, 256, 0, stream>>>(Kb, fc, fs, 8, 1024);
        transpose_k<<<dim3(16, 32), 256, 0, stream>>>(Vb, Vt, 2048, 1024, 1024);
        attn_kernel<<<dim3(16, 32), 256, 0, stream>>>(Qb, Kb, Vt, Qb, 1024);
        for (int s = 0; s < 4; s++) {
            transpose_conv<<<dim3(16, 64), 256, 0, stream>>>(wo, WT, 4096, 4096, s * 1024);
            gemm_bt_g<short, float><<<dim3(8, 16), 256, 0, stream>>>(Qb, WT, out, 4096, 4096, s * 1024);
        }
    }
}